// Round 2
// baseline (1123.471 us; speedup 1.0000x reference)
//
#include <hip/hip_runtime.h>

#define BB 256
#define TT 256
#define CC 256
#define HH 64

// ---------------------------------------------------------------------------
// Kernel A: q/k/v projections (fp32).  16 rows of x per block staged in LDS.
// Thread t: h = t&63, row-group = t>>6 (4 rows each).  Weights (192 KB fp32)
// stay L2-hot; per-c weight loads are coalesced across the wave (h = lane).
// ---------------------------------------------------------------------------
__global__ __launch_bounds__(256) void proj_kernel(
    const float* __restrict__ x,
    const float* __restrict__ Wk, const float* __restrict__ Wq, const float* __restrict__ Wv,
    float* __restrict__ qo, float* __restrict__ ko, float* __restrict__ vo)
{
    const int ROWS = 16;
    __shared__ float xs[ROWS][CC];
    const int tid = threadIdx.x;
    const long row0 = (long)blockIdx.x * ROWS;

    // cooperative load: 16*256 = 4096 floats = 1024 float4, 4 per thread
    const float4* xg = reinterpret_cast<const float4*>(x + row0 * CC);
    float4* xsv = reinterpret_cast<float4*>(&xs[0][0]);
#pragma unroll
    for (int i = 0; i < 4; ++i) {
        xsv[tid + i * 256] = xg[tid + i * 256];
    }
    __syncthreads();

    const int h  = tid & 63;
    const int rg = tid >> 6;
    const float* xr0 = xs[rg * 4 + 0];
    const float* xr1 = xs[rg * 4 + 1];
    const float* xr2 = xs[rg * 4 + 2];
    const float* xr3 = xs[rg * 4 + 3];

    float ak0 = 0.f, ak1 = 0.f, ak2 = 0.f, ak3 = 0.f;
    float aq0 = 0.f, aq1 = 0.f, aq2 = 0.f, aq3 = 0.f;
    float av0 = 0.f, av1 = 0.f, av2 = 0.f, av3 = 0.f;

#pragma unroll 8
    for (int c = 0; c < CC; ++c) {
        const float wk = Wk[c * HH + h];
        const float wq = Wq[c * HH + h];
        const float wv = Wv[c * HH + h];
        const float x0 = xr0[c], x1 = xr1[c], x2 = xr2[c], x3 = xr3[c];
        ak0 += x0 * wk; ak1 += x1 * wk; ak2 += x2 * wk; ak3 += x3 * wk;
        aq0 += x0 * wq; aq1 += x1 * wq; aq2 += x2 * wq; aq3 += x3 * wq;
        av0 += x0 * wv; av1 += x1 * wv; av2 += x2 * wv; av3 += x3 * wv;
    }

    const long r0 = row0 + rg * 4;
    ko[(r0 + 0) * HH + h] = ak0;
    ko[(r0 + 1) * HH + h] = ak1;
    ko[(r0 + 2) * HH + h] = ak2;
    ko[(r0 + 3) * HH + h] = ak3;
    qo[(r0 + 0) * HH + h] = aq0;
    qo[(r0 + 1) * HH + h] = aq1;
    qo[(r0 + 2) * HH + h] = aq2;
    qo[(r0 + 3) * HH + h] = aq3;
    vo[(r0 + 0) * HH + h] = av0;
    vo[(r0 + 1) * HH + h] = av1;
    vo[(r0 + 2) * HH + h] = av2;
    vo[(r0 + 3) * HH + h] = av3;
}

// ---------------------------------------------------------------------------
// Kernel B: one block per (b, t) query row.  Thread s computes
// score(s) = 0.125 * q.k_s + q.rel[s - t + 255]  (s <= t, else -inf),
// full-row softmax in LDS, then (h, s-chunk) split for the PV product.
// ---------------------------------------------------------------------------
__global__ __launch_bounds__(256) void attn_kernel(
    const float* __restrict__ q, const float* __restrict__ k, const float* __restrict__ v,
    const float* __restrict__ rpe, float* __restrict__ out)
{
    const int bt = blockIdx.x;
    const int b  = bt >> 8;
    const int t  = bt & 255;
    const int tid = threadIdx.x;

    __shared__ float qs[HH];
    __shared__ float wei[TT];
    __shared__ float red[256];
    __shared__ float oacc[4][HH];

    if (tid < HH) qs[tid] = q[(long)bt * HH + tid];
    __syncthreads();

    const int s = tid;
    float score = -INFINITY;
    if (s <= t) {
        const float4* k4 = reinterpret_cast<const float4*>(k + (long)(b * TT + s) * HH);
        const float4* r4 = reinterpret_cast<const float4*>(rpe + (long)(s - t + (TT - 1)) * HH);
        float cacc = 0.f, pacc = 0.f;
#pragma unroll
        for (int i = 0; i < 16; ++i) {
            const float4 kv = k4[i];
            const float4 rv = r4[i];
            const float q0 = qs[4 * i + 0], q1 = qs[4 * i + 1];
            const float q2 = qs[4 * i + 2], q3 = qs[4 * i + 3];
            cacc += q0 * kv.x + q1 * kv.y + q2 * kv.z + q3 * kv.w;
            pacc += q0 * rv.x + q1 * rv.y + q2 * rv.z + q3 * rv.w;
        }
        score = cacc * 0.125f + pacc;
    }

    // row max
    red[tid] = score;
    __syncthreads();
#pragma unroll
    for (int off = 128; off > 0; off >>= 1) {
        if (tid < off) red[tid] = fmaxf(red[tid], red[tid + off]);
        __syncthreads();
    }
    const float rowmax = red[0];
    __syncthreads();

    // exp + sum
    const float e = (s <= t) ? __expf(score - rowmax) : 0.f;
    wei[s] = e;
    red[tid] = e;
    __syncthreads();
#pragma unroll
    for (int off = 128; off > 0; off >>= 1) {
        if (tid < off) red[tid] += red[tid + off];
        __syncthreads();
    }
    const float inv = 1.0f / red[0];

    // PV: thread (h = tid&63, chunk = tid>>6) accumulates 64 s-values
    const int h  = tid & 63;
    const int ch = tid >> 6;
    const float* vb = v + (long)b * TT * HH;
    float acc = 0.f;
    const int s0 = ch * 64;
#pragma unroll 8
    for (int i = 0; i < 64; ++i) {
        acc += wei[s0 + i] * vb[(long)(s0 + i) * HH + h];
    }
    oacc[ch][h] = acc;
    __syncthreads();

    if (tid < HH) {
        out[(long)bt * HH + tid] =
            (oacc[0][tid] + oacc[1][tid] + oacc[2][tid] + oacc[3][tid]) * inv;
    }
}

extern "C" void kernel_launch(void* const* d_in, const int* in_sizes, int n_in,
                              void* d_out, int out_size, void* d_ws, size_t ws_size,
                              hipStream_t stream) {
    const float* x   = (const float*)d_in[0];
    const float* Wk  = (const float*)d_in[1];
    const float* Wq  = (const float*)d_in[2];
    const float* Wv  = (const float*)d_in[3];
    const float* rpe = (const float*)d_in[4];
    float* out = (float*)d_out;

    float* qb = (float*)d_ws;                    // [B*T, H]
    float* kb = qb + (size_t)BB * TT * HH;       // [B*T, H]
    float* vb = kb + (size_t)BB * TT * HH;       // [B*T, H]

    proj_kernel<<<dim3(BB * TT / 16), dim3(256), 0, stream>>>(x, Wk, Wq, Wv, qb, kb, vb);
    attn_kernel<<<dim3(BB * TT), dim3(256), 0, stream>>>(qb, kb, vb, rpe, out);
}

// Round 3
// 299.611 us; speedup vs baseline: 3.7498x; 3.7498x over previous
//
#include <hip/hip_runtime.h>

#define BB 256
#define TT 256
#define CC 256
#define HH 64

typedef _Float16 half8 __attribute__((ext_vector_type(8)));
typedef float floatx4 __attribute__((ext_vector_type(4)));

// ---------------------------------------------------------------------------
// Kernel A: q/k/v projections (fp32 in, f16 out).  16 rows of x per block in
// LDS.  Thread t: h = t&63, row-group = t>>6 (4 rows each).
// qh/kh stored [b*T + t][h]; v stored transposed vTh [b][h][t] so the PV
// MFMA B-fragment is a contiguous 16B load.
// ---------------------------------------------------------------------------
__global__ __launch_bounds__(256) void proj_kernel(
    const float* __restrict__ x,
    const float* __restrict__ Wk, const float* __restrict__ Wq, const float* __restrict__ Wv,
    _Float16* __restrict__ qh, _Float16* __restrict__ kh, _Float16* __restrict__ vTh)
{
    const int ROWS = 16;
    __shared__ float xs[ROWS][CC];
    const int tid = threadIdx.x;
    const int row0 = blockIdx.x * ROWS;

    const float4* xg = reinterpret_cast<const float4*>(x + (size_t)row0 * CC);
    float4* xsv = reinterpret_cast<float4*>(&xs[0][0]);
#pragma unroll
    for (int i = 0; i < 4; ++i) xsv[tid + i * 256] = xg[tid + i * 256];
    __syncthreads();

    const int h  = tid & 63;
    const int rg = tid >> 6;
    const float* xr0 = xs[rg * 4 + 0];
    const float* xr1 = xs[rg * 4 + 1];
    const float* xr2 = xs[rg * 4 + 2];
    const float* xr3 = xs[rg * 4 + 3];

    float ak0 = 0.f, ak1 = 0.f, ak2 = 0.f, ak3 = 0.f;
    float aq0 = 0.f, aq1 = 0.f, aq2 = 0.f, aq3 = 0.f;
    float av0 = 0.f, av1 = 0.f, av2 = 0.f, av3 = 0.f;

#pragma unroll 8
    for (int c = 0; c < CC; ++c) {
        const float wk = Wk[c * HH + h];
        const float wq = Wq[c * HH + h];
        const float wv = Wv[c * HH + h];
        const float x0 = xr0[c], x1 = xr1[c], x2 = xr2[c], x3 = xr3[c];
        ak0 += x0 * wk; ak1 += x1 * wk; ak2 += x2 * wk; ak3 += x3 * wk;
        aq0 += x0 * wq; aq1 += x1 * wq; aq2 += x2 * wq; aq3 += x3 * wq;
        av0 += x0 * wv; av1 += x1 * wv; av2 += x2 * wv; av3 += x3 * wv;
    }

    const int r0 = row0 + rg * 4;       // global row (b*T + t)
    const int b  = r0 >> 8;
    const int tr = r0 & 255;

    kh[(size_t)(r0 + 0) * HH + h] = (_Float16)ak0;
    kh[(size_t)(r0 + 1) * HH + h] = (_Float16)ak1;
    kh[(size_t)(r0 + 2) * HH + h] = (_Float16)ak2;
    kh[(size_t)(r0 + 3) * HH + h] = (_Float16)ak3;
    qh[(size_t)(r0 + 0) * HH + h] = (_Float16)aq0;
    qh[(size_t)(r0 + 1) * HH + h] = (_Float16)aq1;
    qh[(size_t)(r0 + 2) * HH + h] = (_Float16)aq2;
    qh[(size_t)(r0 + 3) * HH + h] = (_Float16)aq3;
    _Float16* vrow = vTh + ((size_t)b * HH + h) * TT + tr;
    vrow[0] = (_Float16)av0;
    vrow[1] = (_Float16)av1;
    vrow[2] = (_Float16)av2;
    vrow[3] = (_Float16)av3;
}

// ---------------------------------------------------------------------------
// rpe rows 0..255 -> f16 (causal mask means only d = s-t+255 <= 255 is used)
// ---------------------------------------------------------------------------
__global__ __launch_bounds__(256) void cvt_rpe(const float* __restrict__ rpe,
                                               _Float16* __restrict__ rpeh)
{
    const int i = blockIdx.x * 256 + threadIdx.x;   // 256*64 = 16384 elements
    rpeh[i] = (_Float16)rpe[i];
}

// ---------------------------------------------------------------------------
// Kernel C: P[b*T+t][d] = q_t . rpe_d  (d in [0,256)), f16 out.
// Grid: (b, t0) 64-query tiles; wave w owns 16 t-rows.  MFMA 16x16x32_f16.
// A-frag: Q[m=lane&15][k=quad*8+i]; B-frag: rpe[n=lane&15][k=quad*8+i].
// ---------------------------------------------------------------------------
__global__ __launch_bounds__(256) void pgemm(
    const _Float16* __restrict__ qh, const _Float16* __restrict__ rpeh,
    _Float16* __restrict__ Ph)
{
    const int b   = blockIdx.x >> 2;
    const int t0  = (blockIdx.x & 3) * 64;
    const int w    = threadIdx.x >> 6;
    const int lane = threadIdx.x & 63;
    const int quad = lane >> 4;
    const int l    = lane & 15;
    const int tw   = t0 + 16 * w;

    const half8 qf0 = *(const half8*)(qh + (size_t)(b * TT + tw + l) * HH + quad * 8);
    const half8 qf1 = *(const half8*)(qh + (size_t)(b * TT + tw + l) * HH + 32 + quad * 8);

    floatx4 acc[16];
#pragma unroll
    for (int dt = 0; dt < 16; ++dt) {
        const _Float16* rp = rpeh + (size_t)(dt * 16 + l) * HH + quad * 8;
        const half8 bf0 = *(const half8*)rp;
        const half8 bf1 = *(const half8*)(rp + 32);
        floatx4 z = {0.f, 0.f, 0.f, 0.f};
        z = __builtin_amdgcn_mfma_f32_16x16x32_f16(qf0, bf0, z, 0, 0, 0);
        acc[dt] = __builtin_amdgcn_mfma_f32_16x16x32_f16(qf1, bf1, z, 0, 0, 0);
    }

#pragma unroll
    for (int dt = 0; dt < 16; ++dt) {
#pragma unroll
        for (int r = 0; r < 4; ++r) {
            const int t = tw + quad * 4 + r;
            Ph[(size_t)(b * TT + t) * 256 + dt * 16 + l] = (_Float16)acc[dt][r];
        }
    }
}

// ---------------------------------------------------------------------------
// Kernel D: flash attention.  Block = (b, 64-query tile), 4 waves x 16 rows.
// No __syncthreads: each wave owns its LDS slice.
//   content: S = Q K^T via MFMA (C-layout: row t=quad*4+reg, col s=lane&15)
//   scores:  0.125*S + Ph[t][s-t+255], causal mask, softmax via shfl_xor
//   PV:      exp weights -> f16 LDS (A-layout re-read) x vTh B-frags
// ---------------------------------------------------------------------------
__global__ __launch_bounds__(256) void flash(
    const _Float16* __restrict__ qh, const _Float16* __restrict__ kh,
    const _Float16* __restrict__ vTh, const _Float16* __restrict__ Ph,
    float* __restrict__ out)
{
    __shared__ _Float16 weih[4][16 * 264];   // per-wave [16 rows][256 + 8 pad]

    const int b   = blockIdx.x >> 2;
    const int t0  = (blockIdx.x & 3) * 64;
    const int w    = threadIdx.x >> 6;
    const int lane = threadIdx.x & 63;
    const int quad = lane >> 4;
    const int l    = lane & 15;
    const int tw   = t0 + 16 * w;
    const int stmax = (t0 >> 4) + w;         // last s-tile index (inclusive)
    const int cmax  = (tw + 15) >> 5;        // last PV 32-chunk (inclusive)

    // zero own weih slice (tiles beyond stmax are read by PV chunk cmax)
    unsigned int* wz = (unsigned int*)&weih[w][0];
#pragma unroll
    for (int i = 0; i < 33; ++i) wz[lane + 64 * i] = 0u;

    // Q fragments
    const _Float16* qp = qh + (size_t)(b * TT + tw + l) * HH + quad * 8;
    const half8 qf0 = *(const half8*)qp;
    const half8 qf1 = *(const half8*)(qp + 32);

    // content scores
    floatx4 sacc[16];
#pragma unroll
    for (int st = 0; st < 16; ++st) {
        if (st <= stmax) {
            const _Float16* kp = kh + (size_t)(b * TT + st * 16 + l) * HH + quad * 8;
            const half8 kf0 = *(const half8*)kp;
            const half8 kf1 = *(const half8*)(kp + 32);
            floatx4 z = {0.f, 0.f, 0.f, 0.f};
            z = __builtin_amdgcn_mfma_f32_16x16x32_f16(qf0, kf0, z, 0, 0, 0);
            sacc[st] = __builtin_amdgcn_mfma_f32_16x16x32_f16(qf1, kf1, z, 0, 0, 0);
        }
    }

    // softmax per C-layout row (t = tw + quad*4 + r lives in this lane)
    float inv_r[4];
#pragma unroll
    for (int r = 0; r < 4; ++r) {
        const int t = tw + quad * 4 + r;
        const _Float16* Pr = Ph + (size_t)(b * TT + t) * 256 + (255 - t);
        float sv[16];
        float m = -INFINITY;
#pragma unroll
        for (int st = 0; st < 16; ++st) {
            if (st <= stmax) {
                const int s = l + 16 * st;
                float val = -INFINITY;
                if (s <= t) val = sacc[st][r] * 0.125f + (float)Pr[s];
                sv[st] = val;
                m = fmaxf(m, val);
            }
        }
        m = fmaxf(m, __shfl_xor(m, 1));
        m = fmaxf(m, __shfl_xor(m, 2));
        m = fmaxf(m, __shfl_xor(m, 4));
        m = fmaxf(m, __shfl_xor(m, 8));
        float sum = 0.f;
#pragma unroll
        for (int st = 0; st < 16; ++st) {
            if (st <= stmax) {
                const float e = __expf(sv[st] - m);
                sum += e;
                weih[w][(quad * 4 + r) * 264 + l + 16 * st] = (_Float16)e;
            }
        }
        sum += __shfl_xor(sum, 1);
        sum += __shfl_xor(sum, 2);
        sum += __shfl_xor(sum, 4);
        sum += __shfl_xor(sum, 8);
        inv_r[r] = 1.0f / sum;
    }

    // PV: A-frag from weih (m=lane&15 row, k=quad*8+i), B-frag from vTh rows
    floatx4 oacc[4] = {{0.f,0.f,0.f,0.f},{0.f,0.f,0.f,0.f},
                       {0.f,0.f,0.f,0.f},{0.f,0.f,0.f,0.f}};
#pragma unroll
    for (int c = 0; c < 8; ++c) {
        if (c <= cmax) {
            const half8 af = *(const half8*)&weih[w][l * 264 + c * 32 + quad * 8];
#pragma unroll
            for (int ht = 0; ht < 4; ++ht) {
                const half8 vf = *(const half8*)(vTh +
                    ((size_t)b * HH + ht * 16 + l) * TT + c * 32 + quad * 8);
                oacc[ht] = __builtin_amdgcn_mfma_f32_16x16x32_f16(af, vf, oacc[ht], 0, 0, 0);
            }
        }
    }

    // epilogue: scale rows by 1/sum (same lanes hold inv_r) and store f32
#pragma unroll
    for (int ht = 0; ht < 4; ++ht) {
#pragma unroll
        for (int r = 0; r < 4; ++r) {
            const int t = tw + quad * 4 + r;
            out[(size_t)(b * TT + t) * HH + ht * 16 + l] = oacc[ht][r] * inv_r[r];
        }
    }
}

extern "C" void kernel_launch(void* const* d_in, const int* in_sizes, int n_in,
                              void* d_out, int out_size, void* d_ws, size_t ws_size,
                              hipStream_t stream) {
    const float* x   = (const float*)d_in[0];
    const float* Wk  = (const float*)d_in[1];
    const float* Wq  = (const float*)d_in[2];
    const float* Wv  = (const float*)d_in[3];
    const float* rpe = (const float*)d_in[4];
    float* out = (float*)d_out;

    const size_t NQ = (size_t)BB * TT * HH;          // 4.19M elems
    _Float16* qh   = (_Float16*)d_ws;
    _Float16* kh   = qh + NQ;
    _Float16* vTh  = kh + NQ;
    _Float16* rpeh = vTh + NQ;
    _Float16* Ph   = rpeh + 256 * HH;                // [B*T][256]

    cvt_rpe<<<dim3(64), dim3(256), 0, stream>>>(rpe, rpeh);
    proj_kernel<<<dim3(BB * TT / 16), dim3(256), 0, stream>>>(x, Wk, Wq, Wv, qh, kh, vTh);
    pgemm<<<dim3(BB * 4), dim3(256), 0, stream>>>(qh, rpeh, Ph);
    flash<<<dim3(BB * 4), dim3(256), 0, stream>>>(qh, kh, vTh, Ph, out);
}

// Round 4
// 198.183 us; speedup vs baseline: 5.6689x; 1.5118x over previous
//
#include <hip/hip_runtime.h>

#define BB 256
#define TT 256
#define CC 256
#define HH 64

typedef _Float16 half8 __attribute__((ext_vector_type(8)));
typedef _Float16 half4 __attribute__((ext_vector_type(4)));
typedef float floatx4 __attribute__((ext_vector_type(4)));

// ---------------------------------------------------------------------------
// prep: blocks 0..63   -> rpeh[i] = (f16) rpe[i]           (256*64 elems)
//       blocks 64..255 -> WT[(w*64+n)][k] = (f16) W_w[k][n] (transposed f16)
// Weight order in WT rows: [0..63]=Wk, [64..127]=Wq, [128..191]=Wv.
// ---------------------------------------------------------------------------
__global__ __launch_bounds__(256) void prep(
    const float* __restrict__ rpe,
    const float* __restrict__ Wk, const float* __restrict__ Wq, const float* __restrict__ Wv,
    _Float16* __restrict__ rpeh, _Float16* __restrict__ WT)
{
    const int bid = blockIdx.x, tid = threadIdx.x;
    if (bid < 64) {
        const int i = bid * 256 + tid;
        rpeh[i] = (_Float16)rpe[i];
    } else {
        const int wsel = (bid - 64) >> 6;          // 0=k, 1=q, 2=v
        const int n    = (bid - 64) & 63;
        const float* W = wsel == 0 ? Wk : (wsel == 1 ? Wq : Wv);
        WT[(size_t)(wsel * 64 + n) * 256 + tid] = (_Float16)W[tid * HH + n];
    }
}

// ---------------------------------------------------------------------------
// proj_mfma: q/k/v projections via MFMA 16x16x32_f16.
// Block = 128 rows (4 waves x 32 rows); wave computes [32 x 192] output
// against WT (192 x 256).  A-frags: fp32 x loads converted in-register.
// Outputs: kh/qh [row][h] f16; v transposed vTh [b][h][t] f16 (half4 stores).
// ---------------------------------------------------------------------------
__global__ __launch_bounds__(256) void proj_mfma(
    const float* __restrict__ x, const _Float16* __restrict__ WT,
    _Float16* __restrict__ qh, _Float16* __restrict__ kh, _Float16* __restrict__ vTh)
{
    const int w    = threadIdx.x >> 6;
    const int lane = threadIdx.x & 63;
    const int quad = lane >> 4;
    const int l    = lane & 15;
    const int row0 = blockIdx.x * 128 + w * 32;    // wave's first row

    floatx4 acc[12][2];
#pragma unroll
    for (int nt = 0; nt < 12; ++nt)
#pragma unroll
        for (int rt = 0; rt < 2; ++rt) acc[nt][rt] = (floatx4){0.f, 0.f, 0.f, 0.f};

    const float4* xg = reinterpret_cast<const float4*>(x);  // row stride 64 float4

#pragma unroll
    for (int kk = 0; kk < 8; ++kk) {
        // A fragments for the two 16-row tiles: rows row0+l and row0+16+l
        const size_t base0 = (size_t)(row0 + l) * 64 + kk * 8 + quad * 2;
        const size_t base1 = base0 + 16 * 64;
        const float4 a0lo = xg[base0],     a0hi = xg[base0 + 1];
        const float4 a1lo = xg[base1],     a1hi = xg[base1 + 1];
        half8 af0, af1;
        af0[0] = (_Float16)a0lo.x; af0[1] = (_Float16)a0lo.y;
        af0[2] = (_Float16)a0lo.z; af0[3] = (_Float16)a0lo.w;
        af0[4] = (_Float16)a0hi.x; af0[5] = (_Float16)a0hi.y;
        af0[6] = (_Float16)a0hi.z; af0[7] = (_Float16)a0hi.w;
        af1[0] = (_Float16)a1lo.x; af1[1] = (_Float16)a1lo.y;
        af1[2] = (_Float16)a1lo.z; af1[3] = (_Float16)a1lo.w;
        af1[4] = (_Float16)a1hi.x; af1[5] = (_Float16)a1hi.y;
        af1[6] = (_Float16)a1hi.z; af1[7] = (_Float16)a1hi.w;

#pragma unroll
        for (int nt = 0; nt < 12; ++nt) {
            const half8 bf = *(const half8*)(WT + (size_t)(nt * 16 + l) * 256 + kk * 32 + quad * 8);
            acc[nt][0] = __builtin_amdgcn_mfma_f32_16x16x32_f16(af0, bf, acc[nt][0], 0, 0, 0);
            acc[nt][1] = __builtin_amdgcn_mfma_f32_16x16x32_f16(af1, bf, acc[nt][1], 0, 0, 0);
        }
    }

    // epilogue.  C-layout: row = quad*4 + r, col = l.
    const int bq  = row0 >> 8;        // batch (block's 128 rows stay in one b)
    const int trw = row0 & 255;       // t of wave's first row
#pragma unroll
    for (int nt = 0; nt < 4; ++nt) {
#pragma unroll
        for (int rt = 0; rt < 2; ++rt) {
#pragma unroll
            for (int r = 0; r < 4; ++r) {
                const size_t row = (size_t)row0 + rt * 16 + quad * 4 + r;
                kh[row * HH + nt * 16 + l] = (_Float16)acc[nt][rt][r];
                qh[row * HH + nt * 16 + l] = (_Float16)acc[nt + 4][rt][r];
            }
            half4 vv;
            vv[0] = (_Float16)acc[nt + 8][rt][0];
            vv[1] = (_Float16)acc[nt + 8][rt][1];
            vv[2] = (_Float16)acc[nt + 8][rt][2];
            vv[3] = (_Float16)acc[nt + 8][rt][3];
            *(half4*)(vTh + ((size_t)bq * HH + nt * 16 + l) * TT + trw + rt * 16 + quad * 4) = vv;
        }
    }
}

// ---------------------------------------------------------------------------
// pgemm: P[b*T+t][d] = q_t . rpe_d, f16 out, causal-skipped:
// rows tw..tw+15 only need d >= 240 - tw  ->  dt >= 15 - tw/16.
// ---------------------------------------------------------------------------
__global__ __launch_bounds__(256) void pgemm(
    const _Float16* __restrict__ qh, const _Float16* __restrict__ rpeh,
    _Float16* __restrict__ Ph)
{
    const int b    = blockIdx.x >> 2;
    const int t0   = (blockIdx.x & 3) * 64;
    const int w    = threadIdx.x >> 6;
    const int lane = threadIdx.x & 63;
    const int quad = lane >> 4;
    const int l    = lane & 15;
    const int tw   = t0 + 16 * w;
    const int dtmin = 15 - (tw >> 4);

    const half8 qf0 = *(const half8*)(qh + (size_t)(b * TT + tw + l) * HH + quad * 8);
    const half8 qf1 = *(const half8*)(qh + (size_t)(b * TT + tw + l) * HH + 32 + quad * 8);

    floatx4 acc[16];
#pragma unroll
    for (int dt = 0; dt < 16; ++dt) {
        if (dt >= dtmin) {
            const _Float16* rp = rpeh + (size_t)(dt * 16 + l) * HH + quad * 8;
            const half8 bf0 = *(const half8*)rp;
            const half8 bf1 = *(const half8*)(rp + 32);
            floatx4 z = {0.f, 0.f, 0.f, 0.f};
            z = __builtin_amdgcn_mfma_f32_16x16x32_f16(qf0, bf0, z, 0, 0, 0);
            acc[dt] = __builtin_amdgcn_mfma_f32_16x16x32_f16(qf1, bf1, z, 0, 0, 0);
        }
    }

#pragma unroll
    for (int dt = 0; dt < 16; ++dt) {
        if (dt >= dtmin) {
#pragma unroll
            for (int r = 0; r < 4; ++r) {
                const int t = tw + quad * 4 + r;
                Ph[(size_t)(b * TT + t) * 256 + dt * 16 + l] = (_Float16)acc[dt][r];
            }
        }
    }
}

// ---------------------------------------------------------------------------
// flash: block = (b, 64-query tile), 4 waves x 16 rows, no __syncthreads.
// ---------------------------------------------------------------------------
__global__ __launch_bounds__(256) void flash(
    const _Float16* __restrict__ qh, const _Float16* __restrict__ kh,
    const _Float16* __restrict__ vTh, const _Float16* __restrict__ Ph,
    float* __restrict__ out)
{
    __shared__ _Float16 weih[4][16 * 264];   // per-wave [16 rows][256 + 8 pad]

    const int b    = blockIdx.x >> 2;
    const int t0   = (blockIdx.x & 3) * 64;
    const int w    = threadIdx.x >> 6;
    const int lane = threadIdx.x & 63;
    const int quad = lane >> 4;
    const int l    = lane & 15;
    const int tw   = t0 + 16 * w;
    const int stmax = (t0 >> 4) + w;         // last s-tile index (inclusive)
    const int cmax  = (tw + 15) >> 5;        // last PV 32-chunk (inclusive)

    unsigned int* wz = (unsigned int*)&weih[w][0];
#pragma unroll
    for (int i = 0; i < 33; ++i) wz[lane + 64 * i] = 0u;

    const _Float16* qp = qh + (size_t)(b * TT + tw + l) * HH + quad * 8;
    const half8 qf0 = *(const half8*)qp;
    const half8 qf1 = *(const half8*)(qp + 32);

    floatx4 sacc[16];
#pragma unroll
    for (int st = 0; st < 16; ++st) {
        if (st <= stmax) {
            const _Float16* kp = kh + (size_t)(b * TT + st * 16 + l) * HH + quad * 8;
            const half8 kf0 = *(const half8*)kp;
            const half8 kf1 = *(const half8*)(kp + 32);
            floatx4 z = {0.f, 0.f, 0.f, 0.f};
            z = __builtin_amdgcn_mfma_f32_16x16x32_f16(qf0, kf0, z, 0, 0, 0);
            sacc[st] = __builtin_amdgcn_mfma_f32_16x16x32_f16(qf1, kf1, z, 0, 0, 0);
        }
    }

    float inv_r[4];
#pragma unroll
    for (int r = 0; r < 4; ++r) {
        const int t = tw + quad * 4 + r;
        const _Float16* Pr = Ph + (size_t)(b * TT + t) * 256 + (255 - t);
        float sv[16];
        float m = -INFINITY;
#pragma unroll
        for (int st = 0; st < 16; ++st) {
            if (st <= stmax) {
                const int s = l + 16 * st;
                float val = -INFINITY;
                if (s <= t) val = sacc[st][r] * 0.125f + (float)Pr[s];
                sv[st] = val;
                m = fmaxf(m, val);
            }
        }
        m = fmaxf(m, __shfl_xor(m, 1));
        m = fmaxf(m, __shfl_xor(m, 2));
        m = fmaxf(m, __shfl_xor(m, 4));
        m = fmaxf(m, __shfl_xor(m, 8));
        float sum = 0.f;
#pragma unroll
        for (int st = 0; st < 16; ++st) {
            if (st <= stmax) {
                const float e = __expf(sv[st] - m);
                sum += e;
                weih[w][(quad * 4 + r) * 264 + l + 16 * st] = (_Float16)e;
            }
        }
        sum += __shfl_xor(sum, 1);
        sum += __shfl_xor(sum, 2);
        sum += __shfl_xor(sum, 4);
        sum += __shfl_xor(sum, 8);
        inv_r[r] = 1.0f / sum;
    }

    floatx4 oacc[4] = {{0.f,0.f,0.f,0.f},{0.f,0.f,0.f,0.f},
                       {0.f,0.f,0.f,0.f},{0.f,0.f,0.f,0.f}};
#pragma unroll
    for (int c = 0; c < 8; ++c) {
        if (c <= cmax) {
            const half8 af = *(const half8*)&weih[w][l * 264 + c * 32 + quad * 8];
#pragma unroll
            for (int ht = 0; ht < 4; ++ht) {
                const half8 vf = *(const half8*)(vTh +
                    ((size_t)b * HH + ht * 16 + l) * TT + c * 32 + quad * 8);
                oacc[ht] = __builtin_amdgcn_mfma_f32_16x16x32_f16(af, vf, oacc[ht], 0, 0, 0);
            }
        }
    }

#pragma unroll
    for (int ht = 0; ht < 4; ++ht) {
#pragma unroll
        for (int r = 0; r < 4; ++r) {
            const int t = tw + quad * 4 + r;
            out[(size_t)(b * TT + t) * HH + ht * 16 + l] = oacc[ht][r] * inv_r[r];
        }
    }
}

extern "C" void kernel_launch(void* const* d_in, const int* in_sizes, int n_in,
                              void* d_out, int out_size, void* d_ws, size_t ws_size,
                              hipStream_t stream) {
    const float* x   = (const float*)d_in[0];
    const float* Wk  = (const float*)d_in[1];
    const float* Wq  = (const float*)d_in[2];
    const float* Wv  = (const float*)d_in[3];
    const float* rpe = (const float*)d_in[4];
    float* out = (float*)d_out;

    const size_t NQ = (size_t)BB * TT * HH;
    _Float16* qh   = (_Float16*)d_ws;
    _Float16* kh   = qh + NQ;
    _Float16* vTh  = kh + NQ;
    _Float16* rpeh = vTh + NQ;
    _Float16* WT   = rpeh + 256 * HH;              // [192][256]
    _Float16* Ph   = WT + 192 * 256;               // [B*T][256]

    prep<<<dim3(256), dim3(256), 0, stream>>>(rpe, Wk, Wq, Wv, rpeh, WT);
    proj_mfma<<<dim3(BB * TT / 128), dim3(256), 0, stream>>>(x, WT, qh, kh, vTh);
    pgemm<<<dim3(BB * 4), dim3(256), 0, stream>>>(qh, rpeh, Ph);
    flash<<<dim3(BB * 4), dim3(256), 0, stream>>>(qh, kh, vTh, Ph, out);
}

// Round 5
// 161.093 us; speedup vs baseline: 6.9740x; 1.2302x over previous
//
#include <hip/hip_runtime.h>

#define BB 256
#define TT 256
#define CC 256
#define HH 64

typedef _Float16 half8 __attribute__((ext_vector_type(8)));
typedef _Float16 half4 __attribute__((ext_vector_type(4)));
typedef float floatx4 __attribute__((ext_vector_type(4)));

// ---------------------------------------------------------------------------
// prep: blocks 0..63   -> rpeh[i] = (f16) rpe[i]           (256*64 elems)
//       blocks 64..255 -> WT[(w*64+n)][k] = (f16) W_w[k][n] (transposed f16)
// ---------------------------------------------------------------------------
__global__ __launch_bounds__(256) void prep(
    const float* __restrict__ rpe,
    const float* __restrict__ Wk, const float* __restrict__ Wq, const float* __restrict__ Wv,
    _Float16* __restrict__ rpeh, _Float16* __restrict__ WT)
{
    const int bid = blockIdx.x, tid = threadIdx.x;
    if (bid < 64) {
        const int i = bid * 256 + tid;
        rpeh[i] = (_Float16)rpe[i];
    } else {
        const int wsel = (bid - 64) >> 6;          // 0=k, 1=q, 2=v
        const int n    = (bid - 64) & 63;
        const float* W = wsel == 0 ? Wk : (wsel == 1 ? Wq : Wv);
        WT[(size_t)(wsel * 64 + n) * 256 + tid] = (_Float16)W[tid * HH + n];
    }
}

// ---------------------------------------------------------------------------
// proj_mfma: q/k/v projections via MFMA 16x16x32_f16.
// Block = 128 rows (4 waves x 32 rows); wave computes [32 x 192] output.
// ---------------------------------------------------------------------------
__global__ __launch_bounds__(256) void proj_mfma(
    const float* __restrict__ x, const _Float16* __restrict__ WT,
    _Float16* __restrict__ qh, _Float16* __restrict__ kh, _Float16* __restrict__ vTh)
{
    const int w    = threadIdx.x >> 6;
    const int lane = threadIdx.x & 63;
    const int quad = lane >> 4;
    const int l    = lane & 15;
    const int row0 = blockIdx.x * 128 + w * 32;

    floatx4 acc[12][2];
#pragma unroll
    for (int nt = 0; nt < 12; ++nt)
#pragma unroll
        for (int rt = 0; rt < 2; ++rt) acc[nt][rt] = (floatx4){0.f, 0.f, 0.f, 0.f};

    const float4* xg = reinterpret_cast<const float4*>(x);

#pragma unroll
    for (int kk = 0; kk < 8; ++kk) {
        const size_t base0 = (size_t)(row0 + l) * 64 + kk * 8 + quad * 2;
        const size_t base1 = base0 + 16 * 64;
        const float4 a0lo = xg[base0],     a0hi = xg[base0 + 1];
        const float4 a1lo = xg[base1],     a1hi = xg[base1 + 1];
        half8 af0, af1;
        af0[0] = (_Float16)a0lo.x; af0[1] = (_Float16)a0lo.y;
        af0[2] = (_Float16)a0lo.z; af0[3] = (_Float16)a0lo.w;
        af0[4] = (_Float16)a0hi.x; af0[5] = (_Float16)a0hi.y;
        af0[6] = (_Float16)a0hi.z; af0[7] = (_Float16)a0hi.w;
        af1[0] = (_Float16)a1lo.x; af1[1] = (_Float16)a1lo.y;
        af1[2] = (_Float16)a1lo.z; af1[3] = (_Float16)a1lo.w;
        af1[4] = (_Float16)a1hi.x; af1[5] = (_Float16)a1hi.y;
        af1[6] = (_Float16)a1hi.z; af1[7] = (_Float16)a1hi.w;

#pragma unroll
        for (int nt = 0; nt < 12; ++nt) {
            const half8 bf = *(const half8*)(WT + (size_t)(nt * 16 + l) * 256 + kk * 32 + quad * 8);
            acc[nt][0] = __builtin_amdgcn_mfma_f32_16x16x32_f16(af0, bf, acc[nt][0], 0, 0, 0);
            acc[nt][1] = __builtin_amdgcn_mfma_f32_16x16x32_f16(af1, bf, acc[nt][1], 0, 0, 0);
        }
    }

    const int bq  = row0 >> 8;
    const int trw = row0 & 255;
#pragma unroll
    for (int nt = 0; nt < 4; ++nt) {
#pragma unroll
        for (int rt = 0; rt < 2; ++rt) {
#pragma unroll
            for (int r = 0; r < 4; ++r) {
                const size_t row = (size_t)row0 + rt * 16 + quad * 4 + r;
                kh[row * HH + nt * 16 + l] = (_Float16)acc[nt][rt][r];
                qh[row * HH + nt * 16 + l] = (_Float16)acc[nt + 4][rt][r];
            }
            half4 vv;
            vv[0] = (_Float16)acc[nt + 8][rt][0];
            vv[1] = (_Float16)acc[nt + 8][rt][1];
            vv[2] = (_Float16)acc[nt + 8][rt][2];
            vv[3] = (_Float16)acc[nt + 8][rt][3];
            *(half4*)(vTh + ((size_t)bq * HH + nt * 16 + l) * TT + trw + rt * 16 + quad * 4) = vv;
        }
    }
}

// ---------------------------------------------------------------------------
// flash (pgemm fused): block = (b, 64-query tile), 4 waves x 16 rows, no
// __syncthreads (each wave owns its weih slice).
//   swizzle: b = bid & 255, t0 = (bid >> 8) * 64  -> CU-balanced causal work
//   P:    wave computes P[t][d] = q_t . rpe_d via MFMA (dt >= dtmin) and
//         scatters SKEWED into LDS: weih[row][s], s = d + t - 255
//   QK:   S = Q K^T via MFMA (C-layout row t=quad*4+r, col s=lane&15)
//   soft: val = 0.125*S + P(LDS), causal, shfl_xor softmax, exp overwrites
//         the same LDS slot (same lane reads then writes each element)
//   PV:   A-frags from weih x vTh B-frags, scale rows by 1/sum, store f32
// ---------------------------------------------------------------------------
__global__ __launch_bounds__(256) void flash(
    const _Float16* __restrict__ qh, const _Float16* __restrict__ kh,
    const _Float16* __restrict__ vTh, const _Float16* __restrict__ rpeh,
    float* __restrict__ out)
{
    __shared__ _Float16 weih[4][16 * 264];   // per-wave [16 rows][256 + 8 pad]

    const int b    = blockIdx.x & 255;
    const int t0   = (blockIdx.x >> 8) * 64;
    const int w    = threadIdx.x >> 6;
    const int lane = threadIdx.x & 63;
    const int quad = lane >> 4;
    const int l    = lane & 15;
    const int tw   = t0 + 16 * w;
    const int stmax = (t0 >> 4) + w;         // last s-tile index (inclusive)
    const int cmax  = (tw + 15) >> 5;        // last PV 32-chunk (inclusive)
    const int dtmin = 15 - (tw >> 4);        // first rpe d-tile needed

    // zero own weih slice
    unsigned int* wz = (unsigned int*)&weih[w][0];
#pragma unroll
    for (int i = 0; i < 33; ++i) wz[lane + 64 * i] = 0u;

    // Q fragments
    const _Float16* qp = qh + (size_t)(b * TT + tw + l) * HH + quad * 8;
    const half8 qf0 = *(const half8*)qp;
    const half8 qf1 = *(const half8*)(qp + 32);

    // P-GEMM: C-layout (row=quad*4+r, d=dt*16+l), skewed scatter into LDS
#pragma unroll
    for (int dt = 0; dt < 16; ++dt) {
        if (dt >= dtmin) {
            const _Float16* rp = rpeh + (size_t)(dt * 16 + l) * HH + quad * 8;
            const half8 bf0 = *(const half8*)rp;
            const half8 bf1 = *(const half8*)(rp + 32);
            floatx4 z = {0.f, 0.f, 0.f, 0.f};
            z = __builtin_amdgcn_mfma_f32_16x16x32_f16(qf0, bf0, z, 0, 0, 0);
            const floatx4 pacc = __builtin_amdgcn_mfma_f32_16x16x32_f16(qf1, bf1, z, 0, 0, 0);
#pragma unroll
            for (int r = 0; r < 4; ++r) {
                const int row = quad * 4 + r;
                const int s   = dt * 16 + l + (tw + row) - 255;
                if (s >= 0) weih[w][row * 264 + s] = (_Float16)pacc[r];
            }
        }
    }

    // content scores
    floatx4 sacc[16];
#pragma unroll
    for (int st = 0; st < 16; ++st) {
        if (st <= stmax) {
            const _Float16* kp = kh + (size_t)(b * TT + st * 16 + l) * HH + quad * 8;
            const half8 kf0 = *(const half8*)kp;
            const half8 kf1 = *(const half8*)(kp + 32);
            floatx4 z = {0.f, 0.f, 0.f, 0.f};
            z = __builtin_amdgcn_mfma_f32_16x16x32_f16(qf0, kf0, z, 0, 0, 0);
            sacc[st] = __builtin_amdgcn_mfma_f32_16x16x32_f16(qf1, kf1, z, 0, 0, 0);
        }
    }

    // softmax per C-layout row; P read from LDS, exp overwrites in place
    float inv_r[4];
#pragma unroll
    for (int r = 0; r < 4; ++r) {
        const int row = quad * 4 + r;
        const int t   = tw + row;
        float sv[16];
        float m = -INFINITY;
#pragma unroll
        for (int st = 0; st < 16; ++st) {
            if (st <= stmax) {
                const int s = l + 16 * st;
                float val = -INFINITY;
                if (s <= t) val = sacc[st][r] * 0.125f + (float)weih[w][row * 264 + s];
                sv[st] = val;
                m = fmaxf(m, val);
            }
        }
        m = fmaxf(m, __shfl_xor(m, 1));
        m = fmaxf(m, __shfl_xor(m, 2));
        m = fmaxf(m, __shfl_xor(m, 4));
        m = fmaxf(m, __shfl_xor(m, 8));
        float sum = 0.f;
#pragma unroll
        for (int st = 0; st < 16; ++st) {
            if (st <= stmax) {
                const int s = l + 16 * st;
                float e = 0.f;
                if (s <= t) e = __expf(sv[st] - m);
                sum += e;
                weih[w][row * 264 + s] = (_Float16)e;
            }
        }
        sum += __shfl_xor(sum, 1);
        sum += __shfl_xor(sum, 2);
        sum += __shfl_xor(sum, 4);
        sum += __shfl_xor(sum, 8);
        inv_r[r] = 1.0f / sum;
    }

    // PV: A-frag from weih (m=lane&15 row, k=quad*8+i), B-frag from vTh rows
    floatx4 oacc[4] = {{0.f,0.f,0.f,0.f},{0.f,0.f,0.f,0.f},
                       {0.f,0.f,0.f,0.f},{0.f,0.f,0.f,0.f}};
#pragma unroll
    for (int c = 0; c < 8; ++c) {
        if (c <= cmax) {
            const half8 af = *(const half8*)&weih[w][l * 264 + c * 32 + quad * 8];
#pragma unroll
            for (int ht = 0; ht < 4; ++ht) {
                const half8 vf = *(const half8*)(vTh +
                    ((size_t)b * HH + ht * 16 + l) * TT + c * 32 + quad * 8);
                oacc[ht] = __builtin_amdgcn_mfma_f32_16x16x32_f16(af, vf, oacc[ht], 0, 0, 0);
            }
        }
    }

#pragma unroll
    for (int ht = 0; ht < 4; ++ht) {
#pragma unroll
        for (int r = 0; r < 4; ++r) {
            const int t = tw + quad * 4 + r;
            out[(size_t)(b * TT + t) * HH + ht * 16 + l] = oacc[ht][r] * inv_r[r];
        }
    }
}

extern "C" void kernel_launch(void* const* d_in, const int* in_sizes, int n_in,
                              void* d_out, int out_size, void* d_ws, size_t ws_size,
                              hipStream_t stream) {
    const float* x   = (const float*)d_in[0];
    const float* Wk  = (const float*)d_in[1];
    const float* Wq  = (const float*)d_in[2];
    const float* Wv  = (const float*)d_in[3];
    const float* rpe = (const float*)d_in[4];
    float* out = (float*)d_out;

    const size_t NQ = (size_t)BB * TT * HH;
    _Float16* qh   = (_Float16*)d_ws;
    _Float16* kh   = qh + NQ;
    _Float16* vTh  = kh + NQ;
    _Float16* rpeh = vTh + NQ;
    _Float16* WT   = rpeh + 256 * HH;              // [192][256]

    prep<<<dim3(256), dim3(256), 0, stream>>>(rpe, Wk, Wq, Wv, rpeh, WT);
    proj_mfma<<<dim3(BB * TT / 128), dim3(256), 0, stream>>>(x, WT, qh, kh, vTh);
    flash<<<dim3(BB * 4), dim3(256), 0, stream>>>(qh, kh, vTh, rpeh, out);
}